// Round 7
// baseline (5891.450 us; speedup 1.0000x reference)
//
#include <hip/hip_runtime.h>
#include <math.h>

#define BB 256
#define TT 512
#define DD 256
#define HH 512
#define SS 8
#define G4H 2048
#define BH (BB*HH)          // 131072
#define OUT_BASE ((size_t)BB*TT*DD)
#define XSLOT (32*512)      // u32 per group-slot

typedef _Float16 f16;
typedef __attribute__((ext_vector_type(8)))  _Float16 f16x8;
typedef __attribute__((ext_vector_type(16))) float    f32x16;

__device__ __forceinline__ float sigm(float x) { return 1.f / (1.f + __expf(-x)); }
__device__ __forceinline__ float ftanh(float x) {
  x = fminf(15.f, fmaxf(-15.f, x));
  float e = __expf(-2.f * x);
  return (1.f - e) / (1.f + e);
}

// ---------------- prep kernels ----------------

__global__ __launch_bounds__(256) void prep_wbig16(
    const float* __restrict__ W_ih, const float* __restrict__ W_hh,
    const float* __restrict__ W_lin, f16* __restrict__ Wbig16)
{
  __shared__ float As[64][20];
  __shared__ float Bs[16][68];
  const int n0 = blockIdx.x * 64;
  const int j0 = blockIdx.y * 64;
  const int tid = threadIdx.x;
  const int tn = tid >> 4, tj = tid & 15;
  float acc[4][4] = {};
  for (int k0 = 0; k0 < DD; k0 += 16) {
    { int r = tid >> 2, c = (tid & 3) * 4;
      *(float4*)&As[r][c] = *(const float4*)&W_ih[(size_t)(n0 + r) * DD + k0 + c]; }
    { int r = tid >> 4, c = (tid & 15) * 4;
      *(float4*)&Bs[r][c] = *(const float4*)&W_lin[(size_t)(k0 + r) * HH + j0 + c]; }
    __syncthreads();
    #pragma unroll
    for (int k = 0; k < 16; ++k) {
      float a[4], bv[4];
      #pragma unroll
      for (int i = 0; i < 4; ++i) a[i] = As[tn*4+i][k];
      #pragma unroll
      for (int m = 0; m < 4; ++m) bv[m] = Bs[k][tj*4+m];
      #pragma unroll
      for (int i = 0; i < 4; ++i)
        #pragma unroll
        for (int m = 0; m < 4; ++m)
          acc[i][m] = fmaf(a[i], bv[m], acc[i][m]);
    }
    __syncthreads();
  }
  #pragma unroll
  for (int i = 0; i < 4; ++i) {
    int n = n0 + tn*4 + i;
    #pragma unroll
    for (int m = 0; m < 4; ++m) {
      int j = j0 + tj*4 + m;
      Wbig16[(size_t)n*HH + j] = (f16)(acc[i][m] + W_hh[(size_t)n*HH + j]);
    }
  }
}

__global__ void prep_bias(const float* __restrict__ b_ih, const float* __restrict__ b_hh,
                          const float* __restrict__ W_ih, const float* __restrict__ b_lin,
                          float* __restrict__ bias0, float* __restrict__ bias1)
{
  int n = blockIdx.x * 256 + threadIdx.x;   // grid 8
  float s = b_ih[n] + b_hh[n];
  float d = 0.f;
  for (int k = 0; k < DD; ++k) d = fmaf(W_ih[(size_t)n*DD + k], b_lin[k], d);
  bias0[n] = s;
  bias1[n] = s + d;
}

#define NIH (G4H*DD)
#define NHH (G4H*HH)
__global__ void prep_cvtw(const float* __restrict__ W_ih, const float* __restrict__ W_hh,
                          const float* __restrict__ W_lin,
                          f16* __restrict__ Wih16, f16* __restrict__ Whh16,
                          f16* __restrict__ Wlin16)
{
  int e = blockIdx.x * 256 + threadIdx.x;   // grid 6656
  if (e < NIH) Wih16[e] = (f16)W_ih[e];
  else if (e < NIH + NHH) Whh16[e - NIH] = (f16)W_hh[e - NIH];
  else Wlin16[e - NIH - NHH] = (f16)W_lin[e - NIH - NHH];
}

__global__ void prep_init(const float* __restrict__ x0, const float* __restrict__ h0,
                          const float* __restrict__ c0,
                          const int* __restrict__ w1, const int* __restrict__ w2,
                          float* __restrict__ bh, float* __restrict__ bc,
                          f16* __restrict__ x0hi, f16* __restrict__ x0lo,
                          f16* __restrict__ h0hi, f16* __restrict__ h0lo,
                          float4* __restrict__ stepc,
                          int* __restrict__ flags)
{
  int e = blockIdx.x * 256 + threadIdx.x;   // grid 4096 -> 1048576
  int r = e & (BH - 1);
  bh[e] = h0[r];
  bc[e] = c0[r];
  if (e < BH) {
    float v = h0[e];
    f16 hi = (f16)v;
    h0hi[e] = hi;
    h0lo[e] = (f16)(v - (float)hi);
  }
  if (e < BB*DD) {
    int b = e >> 8, d = e & 255;
    float v = x0[(size_t)b*(TT*DD) + d];
    f16 hi = (f16)v;
    x0hi[e] = hi;
    x0lo[e] = (f16)(v - (float)hi);
  }
  if (e < TT) {
    float a1 = (float)w1[e], a2 = (float)w2[e];
    stepc[e] = make_float4(a1, a2, 1.f / (a1 + a2), 0.f);
  }
  if (e < 256) flags[e] = 0;
}

// ---------------- persistent main kernel ----------------

// stage one group-slot (32 rows x 512 k, u32 = hi|lo<<16) into two swizzled
// LDS planes. 256 threads x 16 iters x 16B.
__device__ __forceinline__ void stageX(const unsigned* __restrict__ Xs,
                                       f16* Ahi, f16* Alo, int tid) {
  #pragma unroll
  for (int i = 0; i < 16; ++i) {
    int lin = i * 256 + tid;            // 4096 granules of 16B
    int r = lin >> 7, c16 = lin & 127;
    const unsigned long long* src = (const unsigned long long*)(Xs + (size_t)r * 512 + c16 * 4);
    unsigned long long v0 = __hip_atomic_load(src,     __ATOMIC_RELAXED, __HIP_MEMORY_SCOPE_AGENT);
    unsigned long long v1 = __hip_atomic_load(src + 1, __ATOMIC_RELAXED, __HIP_MEMORY_SCOPE_AGENT);
    unsigned a0 = (unsigned)v0, a1 = (unsigned)(v0 >> 32);
    unsigned a2 = (unsigned)v1, a3 = (unsigned)(v1 >> 32);
    uint2 hw, lw;
    hw.x = (a0 & 0xffffu) | (a1 << 16);
    lw.x = (a0 >> 16)     | (a1 & 0xffff0000u);
    hw.y = (a2 & 0xffffu) | (a3 << 16);
    lw.y = (a2 >> 16)     | (a3 & 0xffff0000u);
    int off = r * 1024 + ((((c16 >> 1) << 4)) ^ (r << 4)) + ((c16 & 1) << 3);
    *(uint2*)((char*)Ahi + off) = hw;
    *(uint2*)((char*)Alo + off) = lw;
  }
}

// K=512 2-plane GEMM, 2 N-tiles per wave: each A-frag feeds 4 MFMAs.
__device__ __forceinline__ void gemm2(const f16x8 (&wA)[32], const f16x8 (&wB)[32],
                                      const f16* Ahi, const f16* Alo,
                                      int rbase, int kselB, int key,
                                      f32x16& acc0, f32x16& acc1) {
  #pragma unroll
  for (int ks = 0; ks < 32; ++ks) {
    int off = rbase + (((ks << 5) + kselB) ^ key);
    f16x8 ah = *(const f16x8*)((const char*)Ahi + off);
    f16x8 al = *(const f16x8*)((const char*)Alo + off);
    acc0 = __builtin_amdgcn_mfma_f32_32x32x16_f16(ah, wA[ks], acc0, 0, 0, 0);
    acc1 = __builtin_amdgcn_mfma_f32_32x32x16_f16(ah, wB[ks], acc1, 0, 0, 0);
    acc0 = __builtin_amdgcn_mfma_f32_32x32x16_f16(al, wA[ks], acc0, 0, 0, 0);
    acc1 = __builtin_amdgcn_mfma_f32_32x32x16_f16(al, wB[ks], acc1, 0, 0, 0);
  }
}

// 72 blocks x 256 threads (4 waves).
// bid 0..63: gates. grp = bid&7 (batch rows [32g,32g+32)), role = bid>>3 =
//            j-slice [64r, 64r+64) x all 4 gates. wave = gate.
// bid 64..71: out-projection, one per group, lagging on a 4-slot ring.
// Flags: flags[grp*16 + role] (monotonic step count), [grp*16+8] = out block.
__global__ __launch_bounds__(256, 1) void lstm_persist(
    const f16* __restrict__ x0hi, const f16* __restrict__ x0lo,
    const f16* __restrict__ h0hi, const f16* __restrict__ h0lo,
    const float* __restrict__ c0,
    const f16* __restrict__ Wih16, const f16* __restrict__ Whh16,
    const f16* __restrict__ Wbig16, const f16* __restrict__ Wlin16,
    const float* __restrict__ bias0, const float* __restrict__ bias1,
    const float* __restrict__ b_lin,
    const float4* __restrict__ stepc,
    unsigned* __restrict__ X,                     // 4 slots x 8 grp x 32 x 512 u32
    float* __restrict__ bh, float* __restrict__ bc,
    int* __restrict__ flags,
    float* __restrict__ outp)
{
  __shared__ f16 AhiS[32 * HH];     // 32 KB, XOR-swizzled
  __shared__ f16 AloS[32 * HH];     // 32 KB
  __shared__ float gbuf[4 * 2048];  // 32 KB: [gate][32 b][64 j]

  const int tid  = threadIdx.x;
  const int lane = tid & 63;
  const int wv   = tid >> 6;            // wave 0..3
  const int bid  = blockIdx.x;
  const bool isG = bid < 64;
  const int grp  = isG ? (bid & 7) : (bid - 64);
  const int role = bid >> 3;            // gates only: 0..7
  const int b0   = grp * 32;

  const int row   = lane & 31;
  const int ksel8 = (lane >> 5) * 8;
  const int kselB = ksel8 * 2;
  const int rbase = row * 1024;
  const int key   = row << 4;

  int* gflag = flags + grp * 16;

  // ---- persistent W fragments: 2 tiles x K=512 -> 256 VGPR ----
  int n0, n1;
  const f16* wsrc;
  int wldw;
  if (isG) {
    n0 = wv * 512 + role * 64 + row;        // gate wv, tile 0
    n1 = n0 + 32;                           // tile 1
    wsrc = Wbig16; wldw = HH;
  } else {
    n0 = wv * 64 + row;                     // d-cols [64wv, +32)
    n1 = n0 + 32;
    wsrc = Wlin16; wldw = HH;
  }
  f16x8 wA[32], wB[32];
  #pragma unroll
  for (int ks = 0; ks < 32; ++ks) {
    wA[ks] = *(const f16x8*)(wsrc + (size_t)n0 * wldw + ks * 16 + ksel8);
    wB[ks] = *(const f16x8*)(wsrc + (size_t)n1 * wldw + ks * 16 + ksel8);
  }

  if (isG) {
    // ---- per-thread epilogue constants ----
    const int jl = tid & 63;
    const int jg = role * 64 + jl;          // global j (0..511)
    const float bI = bias1[jg], bF = bias1[512 + jg];
    const float bG = bias1[1024 + jg], bO = bias1[1536 + jg];
    float creg[8];
    #pragma unroll
    for (int i = 0; i < 8; ++i)
      creg[i] = c0[(b0 + (tid >> 6) + 4 * i) * HH + jg];

    for (int t = 0; t < TT; ++t) {
      if (t > 0) {
        if (tid < 8) {
          while (__hip_atomic_load(&gflag[tid], __ATOMIC_RELAXED,
                                   __HIP_MEMORY_SCOPE_AGENT) < t)
            __builtin_amdgcn_s_sleep(1);
        } else if (tid == 8 && t >= 4) {
          while (__hip_atomic_load(&gflag[8], __ATOMIC_RELAXED,
                                   __HIP_MEMORY_SCOPE_AGENT) < t - 3)
            __builtin_amdgcn_s_sleep(1);
        }
        __syncthreads();
        stageX(X + (size_t)(((t - 1) & 3) * 8 + grp) * XSLOT, AhiS, AloS, tid);
        __syncthreads();
      }

      // prefetch step constants + skip reads (overlap with GEMM)
      const float4 sc = stepc[t];
      const int pos = t & (SS - 1);
      float shv[8], scv[8];
      #pragma unroll
      for (int i = 0; i < 8; ++i) {
        int bx = pos * BH + (b0 + (tid >> 6) + 4 * i) * HH + jg;
        shv[i] = bh[bx];
        scv[i] = bc[bx];
      }

      f32x16 acc0, acc1;
      #pragma unroll
      for (int i = 0; i < 16; ++i) { acc0[i] = 0.f; acc1[i] = 0.f; }
      if (t == 0) {
        const f16* arh = x0hi + (size_t)(b0 + row) * DD;
        const f16* arl = x0lo + (size_t)(b0 + row) * DD;
        const f16* w0p = Wih16 + (size_t)n0 * DD;
        const f16* w1p = Wih16 + (size_t)n1 * DD;
        #pragma unroll
        for (int ks = 0; ks < 16; ++ks) {         // K=256: x0 @ W_ih^T
          int ko = ks * 16 + ksel8;
          f16x8 w0 = *(const f16x8*)(w0p + ko);
          f16x8 w1 = *(const f16x8*)(w1p + ko);
          f16x8 ah = *(const f16x8*)(arh + ko);
          f16x8 al = *(const f16x8*)(arl + ko);
          acc0 = __builtin_amdgcn_mfma_f32_32x32x16_f16(ah, w0, acc0, 0, 0, 0);
          acc1 = __builtin_amdgcn_mfma_f32_32x32x16_f16(ah, w1, acc1, 0, 0, 0);
          acc0 = __builtin_amdgcn_mfma_f32_32x32x16_f16(al, w0, acc0, 0, 0, 0);
          acc1 = __builtin_amdgcn_mfma_f32_32x32x16_f16(al, w1, acc1, 0, 0, 0);
        }
        const f16* brh = h0hi + (size_t)(b0 + row) * HH;
        const f16* brl = h0lo + (size_t)(b0 + row) * HH;
        const f16* q0p = Whh16 + (size_t)n0 * HH;
        const f16* q1p = Whh16 + (size_t)n1 * HH;
        #pragma unroll
        for (int ks = 0; ks < 32; ++ks) {         // K=512: h0 @ W_hh^T
          int ko = ks * 16 + ksel8;
          f16x8 w0 = *(const f16x8*)(q0p + ko);
          f16x8 w1 = *(const f16x8*)(q1p + ko);
          f16x8 ah = *(const f16x8*)(brh + ko);
          f16x8 al = *(const f16x8*)(brl + ko);
          acc0 = __builtin_amdgcn_mfma_f32_32x32x16_f16(ah, w0, acc0, 0, 0, 0);
          acc1 = __builtin_amdgcn_mfma_f32_32x32x16_f16(ah, w1, acc1, 0, 0, 0);
          acc0 = __builtin_amdgcn_mfma_f32_32x32x16_f16(al, w0, acc0, 0, 0, 0);
          acc1 = __builtin_amdgcn_mfma_f32_32x32x16_f16(al, w1, acc1, 0, 0, 0);
        }
      } else {
        gemm2(wA, wB, AhiS, AloS, rbase, kselB, key, acc0, acc1);
      }

      // acc -> gbuf [gate][b][j]; wave wv = gate
      {
        const int col = lane & 31;
        #pragma unroll
        for (int rg = 0; rg < 16; ++rg) {
          int m = (rg & 3) + ((rg >> 2) << 3) + ((lane >> 5) << 2);
          gbuf[wv * 2048 + m * 64 + col]      = acc0[rg];
          gbuf[wv * 2048 + m * 64 + 32 + col] = acc1[rg];
        }
      }
      __syncthreads();

      // fused elementwise LSTM + skip combine
      const float a1 = sc.x, a2 = sc.y, nrm = sc.z;
      float baI = bI, baF = bF, baG = bG, baO = bO;
      if (t == 0) {
        baI = bias0[jg];        baF = bias0[512 + jg];
        baG = bias0[1024 + jg]; baO = bias0[1536 + jg];
      }
      unsigned* Xw = X + (size_t)((t & 3) * 8 + grp) * XSLOT;
      #pragma unroll
      for (int i = 0; i < 8; ++i) {
        int bl = (tid >> 6) + 4 * i;
        int gidx = bl * 64 + jl;
        int eidx = (b0 + bl) * HH + jg;
        float pi = gbuf[gidx]        + baI;
        float pf = gbuf[2048 + gidx] + baF;
        float pg = gbuf[4096 + gidx] + baG;
        float po = gbuf[6144 + gidx] + baO;
        float i_ = sigm(pi), f_ = sigm(pf), o_ = sigm(po), g_ = ftanh(pg);
        float cnew = fmaf(f_, creg[i], i_ * g_);
        float hnew = o_ * ftanh(cnew);
        float ch = (a1 * hnew + a2 * ftanh(shv[i])) * nrm;
        float cc = (a1 * cnew + a2 * ftanh(scv[i])) * nrm;
        creg[i] = cc;
        int bx = pos * BH + eidx;
        bh[bx] = hnew;
        bc[bx] = cnew;
        f16 chh = (f16)ch;
        f16 chl = (f16)(ch - (float)chh);
        unsigned u = (unsigned)*(unsigned short*)&chh |
                     ((unsigned)*(unsigned short*)&chl << 16);
        __hip_atomic_store(&Xw[bl * 512 + jg], u, __ATOMIC_RELAXED,
                           __HIP_MEMORY_SCOPE_AGENT);
        if (t == TT - 1) {
          __builtin_nontemporal_store(ch, &outp[OUT_BASE + eidx]);        // h_fin
          __builtin_nontemporal_store(cc, &outp[OUT_BASE + BH + eidx]);   // c_fin
        }
      }
      __syncthreads();           // drains all stores (vmcnt 0) before flag
      if (tid == 0)
        __hip_atomic_store(&gflag[role], t + 1, __ATOMIC_RELAXED,
                           __HIP_MEMORY_SCOPE_AGENT);
    }
  } else {
    // ---------- lagging out-projection block (one per group) ----------
    const float bld0 = b_lin[wv * 64 + row];
    const float bld1 = b_lin[wv * 64 + 32 + row];
    for (int s = 0; s < TT; ++s) {
      if (tid < 8) {
        while (__hip_atomic_load(&gflag[tid], __ATOMIC_RELAXED,
                                 __HIP_MEMORY_SCOPE_AGENT) < s + 1)
          __builtin_amdgcn_s_sleep(1);
      }
      __syncthreads();
      stageX(X + (size_t)((s & 3) * 8 + grp) * XSLOT, AhiS, AloS, tid);
      __syncthreads();
      f32x16 acc0, acc1;
      #pragma unroll
      for (int i = 0; i < 16; ++i) { acc0[i] = 0.f; acc1[i] = 0.f; }
      gemm2(wA, wB, AhiS, AloS, rbase, kselB, key, acc0, acc1);
      const int col = lane & 31;
      #pragma unroll
      for (int rg = 0; rg < 16; ++rg) {
        int m = (rg & 3) + ((rg >> 2) << 3) + ((lane >> 5) << 2);
        size_t base = (size_t)(b0 + m) * (TT * DD) + (size_t)s * DD + wv * 64 + col;
        __builtin_nontemporal_store(acc0[rg] + bld0, &outp[base]);
        __builtin_nontemporal_store(acc1[rg] + bld1, &outp[base + 32]);
      }
      __syncthreads();           // drains NT stores before flag
      if (tid == 0)
        __hip_atomic_store(&gflag[8], s + 1, __ATOMIC_RELAXED,
                           __HIP_MEMORY_SCOPE_AGENT);
    }
  }
}

// ---------------- host launch ----------------

extern "C" void kernel_launch(void* const* d_in, const int* in_sizes, int n_in,
                              void* d_out, int out_size, void* d_ws, size_t ws_size,
                              hipStream_t stream)
{
  const float* x0    = (const float*)d_in[0];
  const float* h0    = (const float*)d_in[1];
  const float* c0    = (const float*)d_in[2];
  const float* W_ih  = (const float*)d_in[3];
  const float* W_hh  = (const float*)d_in[4];
  const float* b_ih  = (const float*)d_in[5];
  const float* b_hh  = (const float*)d_in[6];
  const float* W_lin = (const float*)d_in[7];
  const float* b_lin = (const float*)d_in[8];
  const int*   w1    = (const int*)d_in[9];
  const int*   w2    = (const int*)d_in[10];

  char* p = (char*)d_ws;
  f16* Wbig16 = (f16*)p;            p += (size_t)G4H*HH*2;
  f16* Wih16  = (f16*)p;            p += (size_t)G4H*DD*2;
  f16* Whh16  = (f16*)p;            p += (size_t)G4H*HH*2;
  f16* Wlin16 = (f16*)p;            p += (size_t)DD*HH*2;
  f16* x0hi   = (f16*)p;            p += (size_t)BB*DD*2;
  f16* x0lo   = (f16*)p;            p += (size_t)BB*DD*2;
  f16* h0hi   = (f16*)p;            p += (size_t)BH*2;
  f16* h0lo   = (f16*)p;            p += (size_t)BH*2;
  unsigned* X = (unsigned*)p;       p += (size_t)4*8*XSLOT*4;   // 2 MB
  float* bh   = (float*)p;          p += (size_t)SS*BH*4;
  float* bc   = (float*)p;          p += (size_t)SS*BH*4;
  float* bias0= (float*)p;          p += G4H*4;
  float* bias1= (float*)p;          p += G4H*4;
  float4* stepc = (float4*)p;       p += (size_t)TT*16;
  int*  flags = (int*)p;            p += 256*4;
  float* outp = (float*)d_out;

  hipLaunchKernelGGL(prep_wbig16, dim3(32, 8), dim3(256), 0, stream,
                     W_ih, W_hh, W_lin, Wbig16);
  hipLaunchKernelGGL(prep_bias, dim3(8), dim3(256), 0, stream,
                     b_ih, b_hh, W_ih, b_lin, bias0, bias1);
  hipLaunchKernelGGL(prep_cvtw, dim3(6656), dim3(256), 0, stream,
                     W_ih, W_hh, W_lin, Wih16, Whh16, Wlin16);
  hipLaunchKernelGGL(prep_init, dim3(4096), dim3(256), 0, stream,
                     x0, h0, c0, w1, w2, bh, bc, x0hi, x0lo, h0hi, h0lo, stepc, flags);

  hipLaunchKernelGGL(lstm_persist, dim3(72), dim3(256), 0, stream,
                     x0hi, x0lo, h0hi, h0lo, c0, Wih16, Whh16, Wbig16, Wlin16,
                     bias0, bias1, b_lin, stepc, X, bh, bc, flags, outp);
}

// Round 8
// 3212.144 us; speedup vs baseline: 1.8341x; 1.8341x over previous
//
#include <hip/hip_runtime.h>
#include <math.h>

#define BB 256
#define TT 512
#define DD 256
#define HH 512
#define SS 8
#define G4H 2048
#define BH (BB*HH)          // 131072
#define OUT_BASE ((size_t)BB*TT*DD)
#define XSLOT_U32 16384     // 64 KB per group-slot: hi plane 8192 u32 + lo plane 8192 u32

typedef _Float16 f16;
typedef __attribute__((ext_vector_type(8)))  _Float16 f16x8;
typedef __attribute__((ext_vector_type(16))) float    f32x16;

__device__ __forceinline__ float sigm(float x) { return 1.f / (1.f + __expf(-x)); }
__device__ __forceinline__ float ftanh(float x) {
  x = fminf(15.f, fmaxf(-15.f, x));
  float e = __expf(-2.f * x);
  return (1.f - e) / (1.f + e);
}

// ---------------- prep kernels ----------------

__global__ __launch_bounds__(256) void prep_wbig16(
    const float* __restrict__ W_ih, const float* __restrict__ W_hh,
    const float* __restrict__ W_lin, f16* __restrict__ Wbig16)
{
  __shared__ float As[64][20];
  __shared__ float Bs[16][68];
  const int n0 = blockIdx.x * 64;
  const int j0 = blockIdx.y * 64;
  const int tid = threadIdx.x;
  const int tn = tid >> 4, tj = tid & 15;
  float acc[4][4] = {};
  for (int k0 = 0; k0 < DD; k0 += 16) {
    { int r = tid >> 2, c = (tid & 3) * 4;
      *(float4*)&As[r][c] = *(const float4*)&W_ih[(size_t)(n0 + r) * DD + k0 + c]; }
    { int r = tid >> 4, c = (tid & 15) * 4;
      *(float4*)&Bs[r][c] = *(const float4*)&W_lin[(size_t)(k0 + r) * HH + j0 + c]; }
    __syncthreads();
    #pragma unroll
    for (int k = 0; k < 16; ++k) {
      float a[4], bv[4];
      #pragma unroll
      for (int i = 0; i < 4; ++i) a[i] = As[tn*4+i][k];
      #pragma unroll
      for (int m = 0; m < 4; ++m) bv[m] = Bs[k][tj*4+m];
      #pragma unroll
      for (int i = 0; i < 4; ++i)
        #pragma unroll
        for (int m = 0; m < 4; ++m)
          acc[i][m] = fmaf(a[i], bv[m], acc[i][m]);
    }
    __syncthreads();
  }
  #pragma unroll
  for (int i = 0; i < 4; ++i) {
    int n = n0 + tn*4 + i;
    #pragma unroll
    for (int m = 0; m < 4; ++m) {
      int j = j0 + tj*4 + m;
      Wbig16[(size_t)n*HH + j] = (f16)(acc[i][m] + W_hh[(size_t)n*HH + j]);
    }
  }
}

__global__ void prep_bias(const float* __restrict__ b_ih, const float* __restrict__ b_hh,
                          const float* __restrict__ W_ih, const float* __restrict__ b_lin,
                          float* __restrict__ bias0, float* __restrict__ bias1)
{
  int n = blockIdx.x * 256 + threadIdx.x;   // grid 8
  float s = b_ih[n] + b_hh[n];
  float d = 0.f;
  for (int k = 0; k < DD; ++k) d = fmaf(W_ih[(size_t)n*DD + k], b_lin[k], d);
  bias0[n] = s;
  bias1[n] = s + d;
}

#define NIH (G4H*DD)
#define NHH (G4H*HH)
__global__ void prep_cvtw(const float* __restrict__ W_ih, const float* __restrict__ W_hh,
                          const float* __restrict__ W_lin,
                          f16* __restrict__ Wih16, f16* __restrict__ Whh16,
                          f16* __restrict__ Wlin16)
{
  int e = blockIdx.x * 256 + threadIdx.x;   // grid 6656
  if (e < NIH) Wih16[e] = (f16)W_ih[e];
  else if (e < NIH + NHH) Whh16[e - NIH] = (f16)W_hh[e - NIH];
  else Wlin16[e - NIH - NHH] = (f16)W_lin[e - NIH - NHH];
}

__global__ void prep_init(const float* __restrict__ x0, const float* __restrict__ h0,
                          const float* __restrict__ c0,
                          const int* __restrict__ w1, const int* __restrict__ w2,
                          float* __restrict__ bh, float* __restrict__ bc,
                          f16* __restrict__ x0hi, f16* __restrict__ x0lo,
                          f16* __restrict__ h0hi, f16* __restrict__ h0lo,
                          float4* __restrict__ stepc,
                          int* __restrict__ flags)
{
  int e = blockIdx.x * 256 + threadIdx.x;   // grid 4096 -> 1048576
  int r = e & (BH - 1);
  bh[e] = h0[r];
  bc[e] = c0[r];
  if (e < BH) {
    float v = h0[e];
    f16 hi = (f16)v;
    h0hi[e] = hi;
    h0lo[e] = (f16)(v - (float)hi);
  }
  if (e < BB*DD) {
    int b = e >> 8, d = e & 255;
    float v = x0[(size_t)b*(TT*DD) + d];
    f16 hi = (f16)v;
    x0hi[e] = hi;
    x0lo[e] = (f16)(v - (float)hi);
  }
  if (e < TT) {
    float a1 = (float)w1[e], a2 = (float)w2[e];
    stepc[e] = make_float4(a1, a2, 1.f / (a1 + a2), 0.f);
  }
  if (e < 256) flags[e] = 0;
}

// ---------------- persistent main kernel ----------------

// Stage one 64 KB group-slot (hi plane 32 KB + lo plane 32 KB) into linear LDS
// via global_load_lds (16B/lane, fire-and-forget, sc0|sc1 so L3-coherent reads).
// Bank-conflict XOR swizzle is applied on the per-lane GLOBAL source address.
__device__ __forceinline__ void stageG(const unsigned* __restrict__ Xs,
                                       f16* lds, int tid) {
  const int lane = tid & 63;
  const int wv = tid >> 6;
  #pragma unroll
  for (int i = 0; i < 8; ++i) {
    int q = wv * 8 + i;                 // 0..63, wave-uniform
    int G = q * 64 + lane;              // granule 0..4095 (16B each)
    int plane = G >> 11;                // 0 = hi, 1 = lo
    int gg = G & 2047;
    int r = gg >> 6, c = gg & 63;       // row 0..31, granule-in-row 0..63
    const char* src = (const char*)Xs + ((size_t)plane * 32768 +
        (size_t)r * 1024 + (size_t)(((c ^ (r & 31)) & 63) << 4));
    __builtin_amdgcn_global_load_lds(
        (const __attribute__((address_space(1))) void*)src,
        (__attribute__((address_space(3))) void*)((char*)lds + q * 1024),
        16, 0, 0x11 /* sc0|sc1 */);
  }
}

// K=512 hi+lo single-N-tile MFMA GEMM from swizzled LDS, W frags in registers.
__device__ __forceinline__ f32x16 gemmS(const f16x8 (&w)[32], const f16* lds, int lane) {
  const int row = lane & 31;
  const int sel = lane >> 5;
  const int rb  = row * 1024;
  const int key = row & 31;
  f32x16 acc;
  #pragma unroll
  for (int i = 0; i < 16; ++i) acc[i] = 0.f;
  #pragma unroll
  for (int ks = 0; ks < 32; ++ks) {
    int gk = 2 * ks + sel;                       // granule 0..63 (XOR flips low 5 bits)
    int off = rb + (((gk & 31) ^ key) << 4) + ((gk & 32) << 4);
    f16x8 ah = *(const f16x8*)((const char*)lds + off);
    f16x8 al = *(const f16x8*)((const char*)lds + 32768 + off);
    acc = __builtin_amdgcn_mfma_f32_32x32x16_f16(ah, w[ks], acc, 0, 0, 0);
    acc = __builtin_amdgcn_mfma_f32_32x32x16_f16(al, w[ks], acc, 0, 0, 0);
  }
  return acc;
}

// 72 blocks x 512 threads (8 waves).
// bid 0..63: gates. grp = bid&7 owns batch rows [32g,32g+32); role = bid>>3 owns
//            j-slice [64r,64r+64) x 4 gates (wave wv: gate wv&3, j-half wv>>2).
// bid 64..71: out-projection block per group, lagging on a 4-slot ring.
// flags[grp*16 + r] = steps completed by gates block r; [grp*16+8] = out block.
__global__ __launch_bounds__(512, 2) void lstm_persist(
    const f16* __restrict__ x0hi, const f16* __restrict__ x0lo,
    const f16* __restrict__ h0hi, const f16* __restrict__ h0lo,
    const float* __restrict__ c0,
    const f16* __restrict__ Wih16, const f16* __restrict__ Whh16,
    const f16* __restrict__ Wbig16, const f16* __restrict__ Wlin16,
    const float* __restrict__ bias0, const float* __restrict__ bias1,
    const float* __restrict__ b_lin,
    const float4* __restrict__ stepc,
    unsigned* __restrict__ X,                 // 4 slots x 8 grp x XSLOT_U32
    float* __restrict__ bh, float* __restrict__ bc,
    int* __restrict__ flags,
    float* __restrict__ outp)
{
  __shared__ f16 LdsA[32768];       // 64 KB: hi plane 32 KB | lo plane 32 KB
  __shared__ float gbuf[8192];      // 32 KB: [gate][32 b][64 j]

  const int tid  = threadIdx.x;
  const int lane = tid & 63;
  const int wv   = tid >> 6;            // wave 0..7
  const int bid  = blockIdx.x;
  const bool isG = bid < 64;
  const int grp  = isG ? (bid & 7) : (bid - 64);
  const int role = bid >> 3;            // gates only: 0..7
  const int b0   = grp * 32;
  const int row  = lane & 31;
  const int ksel8 = (lane >> 5) * 8;

  int* gflag = flags + grp * 16;

  // ---- persistent W fragments (1 N-tile x K=512 -> 128 VGPR) ----
  int wrow;
  const f16* wbase;
  if (isG) {
    wrow  = (wv & 3) * 512 + role * 64 + (wv >> 2) * 32 + row;  // W_big row
    wbase = Wbig16 + (size_t)wrow * HH;
  } else {
    wrow  = wv * 32 + row;                                      // W_lin row (d-col)
    wbase = Wlin16 + (size_t)wrow * HH;
  }
  f16x8 wreg[32];
  #pragma unroll
  for (int ks = 0; ks < 32; ++ks)
    wreg[ks] = *(const f16x8*)(wbase + ks * 16 + ksel8);

  if (isG) {
    // ---- per-thread epilogue constants ----
    int   eidx[4];
    float creg[4];
    const int jl = tid & 63;                 // c = i*512+tid -> jl = c&63
    const int jg = role * 64 + jl;
    const float bI = bias1[jg],        bF = bias1[512 + jg];
    const float bG = bias1[1024 + jg], bO = bias1[1536 + jg];
    #pragma unroll
    for (int i = 0; i < 4; ++i) {
      int c = i * 512 + tid;
      int bl = c >> 6;
      eidx[i] = (b0 + bl) * HH + jg;
      creg[i] = c0[eidx[i]];
    }

    for (int t = 0; t < TT; ++t) {
      if (t > 0) {
        // wait for all 8 gates blocks of this group; lane 8 guards slot reuse
        if (tid < 8) {
          while (__hip_atomic_load(&gflag[tid], __ATOMIC_RELAXED,
                                   __HIP_MEMORY_SCOPE_AGENT) < t)
            __builtin_amdgcn_s_sleep(1);
        } else if (tid == 8 && t >= 4) {
          while (__hip_atomic_load(&gflag[8], __ATOMIC_RELAXED,
                                   __HIP_MEMORY_SCOPE_AGENT) < t - 3)
            __builtin_amdgcn_s_sleep(1);
        }
        __syncthreads();
        stageG(X + (size_t)(((t - 1) & 3) * 8 + grp) * XSLOT_U32, LdsA, tid);
      }

      // prefetch step constants + skip reads (overlap with staging flight)
      const float4 sc = stepc[t];
      const int pos = t & (SS - 1);
      float shv[4], scv[4];
      #pragma unroll
      for (int i = 0; i < 4; ++i) {
        int bx = pos * BH + eidx[i];
        shv[i] = bh[bx];
        scv[i] = bc[bx];
      }

      f32x16 acc;
      if (t == 0) {
        #pragma unroll
        for (int i = 0; i < 16; ++i) acc[i] = 0.f;
        const f16* arh = x0hi + (size_t)(b0 + row) * DD;
        const f16* arl = x0lo + (size_t)(b0 + row) * DD;
        const f16* w1p = Wih16 + (size_t)wrow * DD;
        #pragma unroll
        for (int ks = 0; ks < 16; ++ks) {         // K=256: x0 @ W_ih^T
          int ko = ks * 16 + ksel8;
          f16x8 w = *(const f16x8*)(w1p + ko);
          acc = __builtin_amdgcn_mfma_f32_32x32x16_f16(*(const f16x8*)(arh + ko), w, acc, 0,0,0);
          acc = __builtin_amdgcn_mfma_f32_32x32x16_f16(*(const f16x8*)(arl + ko), w, acc, 0,0,0);
        }
        const f16* brh = h0hi + (size_t)(b0 + row) * HH;
        const f16* brl = h0lo + (size_t)(b0 + row) * HH;
        const f16* w2p = Whh16 + (size_t)wrow * HH;
        #pragma unroll
        for (int ks = 0; ks < 32; ++ks) {         // K=512: h0 @ W_hh^T
          int ko = ks * 16 + ksel8;
          f16x8 w = *(const f16x8*)(w2p + ko);
          acc = __builtin_amdgcn_mfma_f32_32x32x16_f16(*(const f16x8*)(brh + ko), w, acc, 0,0,0);
          acc = __builtin_amdgcn_mfma_f32_32x32x16_f16(*(const f16x8*)(brl + ko), w, acc, 0,0,0);
        }
      } else {
        __syncthreads();                 // staging complete (vmcnt drained here)
        acc = gemmS(wreg, LdsA, lane);
      }

      // acc -> gbuf [gate][b][j]
      {
        const int col = lane & 31;
        const int g4 = wv & 3, jh = wv >> 2;
        #pragma unroll
        for (int rg = 0; rg < 16; ++rg) {
          int m = (rg & 3) + ((rg >> 2) << 3) + ((lane >> 5) << 2);
          gbuf[g4 * 2048 + m * 64 + jh * 32 + col] = acc[rg];
        }
      }
      __syncthreads();

      // fused elementwise LSTM + skip combine; publish X first, flag, then rest
      const float a1 = sc.x, a2 = sc.y, nrm = sc.z;
      float baI = bI, baF = bF, baG = bG, baO = bO;
      if (t == 0) {
        baI = bias0[jg];        baF = bias0[512 + jg];
        baG = bias0[1024 + jg]; baO = bias0[1536 + jg];
      }
      unsigned* Xw = X + (size_t)((t & 3) * 8 + grp) * XSLOT_U32;
      float hnv[4], cnv[4], chv[4], ccv[4];
      #pragma unroll
      for (int i = 0; i < 4; ++i) {
        int c = i * 512 + tid;
        int bl = c >> 6;
        float pi = gbuf[c]        + baI;
        float pf = gbuf[2048 + c] + baF;
        float pg = gbuf[4096 + c] + baG;
        float po = gbuf[6144 + c] + baO;
        float i_ = sigm(pi), f_ = sigm(pf), o_ = sigm(po), g_ = ftanh(pg);
        float cnew = fmaf(f_, creg[i], i_ * g_);
        float hnew = o_ * ftanh(cnew);
        float ch = (a1 * hnew + a2 * ftanh(shv[i])) * nrm;
        float cc = (a1 * cnew + a2 * ftanh(scv[i])) * nrm;
        creg[i] = cc;
        hnv[i] = hnew; cnv[i] = cnew; chv[i] = ch; ccv[i] = cc;
        // pack hi/lo pairs with neighbor lane; even lane -> hi plane, odd -> lo
        f16 chh = (f16)ch;
        f16 chl = (f16)(ch - (float)chh);
        unsigned packed = (unsigned)*(unsigned short*)&chh |
                          ((unsigned)*(unsigned short*)&chl << 16);
        unsigned part = (unsigned)__shfl_xor((int)packed, 1);
        unsigned sval;
        unsigned uoff;
        if ((tid & 1) == 0) { sval = (packed & 0xffffu) | (part << 16);
                              uoff = bl * 256 + (jg >> 1); }
        else                { sval = (part >> 16) | (packed & 0xffff0000u);
                              uoff = 8192 + bl * 256 + (jg >> 1); }
        __hip_atomic_store(&Xw[uoff], sval, __ATOMIC_RELAXED,
                           __HIP_MEMORY_SCOPE_AGENT);
      }
      __syncthreads();                 // drains X stores of all waves (vmcnt 0)
      if (tid == 0)
        __hip_atomic_store(&gflag[role], t + 1, __ATOMIC_RELAXED,
                           __HIP_MEMORY_SCOPE_AGENT);
      // block-private skip-buffer writes + finals AFTER the flag (drain overlaps)
      #pragma unroll
      for (int i = 0; i < 4; ++i) {
        int bx = pos * BH + eidx[i];
        bh[bx] = hnv[i];
        bc[bx] = cnv[i];
        if (t == TT - 1) {
          __builtin_nontemporal_store(chv[i], &outp[OUT_BASE + eidx[i]]);       // h_fin
          __builtin_nontemporal_store(ccv[i], &outp[OUT_BASE + BH + eidx[i]]);  // c_fin
        }
      }
    }
  } else {
    // ---------- lagging out-projection block (one per group) ----------
    const float bld = b_lin[wrow];
    for (int s = 0; s < TT; ++s) {
      if (tid < 8) {
        while (__hip_atomic_load(&gflag[tid], __ATOMIC_RELAXED,
                                 __HIP_MEMORY_SCOPE_AGENT) < s + 1)
          __builtin_amdgcn_s_sleep(1);
      }
      __syncthreads();
      stageG(X + (size_t)((s & 3) * 8 + grp) * XSLOT_U32, LdsA, tid);
      __syncthreads();                 // staging complete
      f32x16 acc = gemmS(wreg, LdsA, lane);
      __syncthreads();                 // all waves' ds_reads of the slot done
      if (tid == 0)
        __hip_atomic_store(&gflag[8], s + 1, __ATOMIC_RELAXED,
                           __HIP_MEMORY_SCOPE_AGENT);
      const size_t tbase = (size_t)s * DD + wrow;
      #pragma unroll
      for (int rg = 0; rg < 16; ++rg) {
        int m = (rg & 3) + ((rg >> 2) << 3) + ((lane >> 5) << 2);
        __builtin_nontemporal_store(acc[rg] + bld,
                                    &outp[(size_t)(b0 + m) * (TT*DD) + tbase]);
      }
    }
  }
}

// ---------------- host launch ----------------

extern "C" void kernel_launch(void* const* d_in, const int* in_sizes, int n_in,
                              void* d_out, int out_size, void* d_ws, size_t ws_size,
                              hipStream_t stream)
{
  const float* x0    = (const float*)d_in[0];
  const float* h0    = (const float*)d_in[1];
  const float* c0    = (const float*)d_in[2];
  const float* W_ih  = (const float*)d_in[3];
  const float* W_hh  = (const float*)d_in[4];
  const float* b_ih  = (const float*)d_in[5];
  const float* b_hh  = (const float*)d_in[6];
  const float* W_lin = (const float*)d_in[7];
  const float* b_lin = (const float*)d_in[8];
  const int*   w1    = (const int*)d_in[9];
  const int*   w2    = (const int*)d_in[10];

  char* p = (char*)d_ws;
  f16* Wbig16 = (f16*)p;            p += (size_t)G4H*HH*2;
  f16* Wih16  = (f16*)p;            p += (size_t)G4H*DD*2;
  f16* Whh16  = (f16*)p;            p += (size_t)G4H*HH*2;
  f16* Wlin16 = (f16*)p;            p += (size_t)DD*HH*2;
  f16* x0hi   = (f16*)p;            p += (size_t)BB*DD*2;
  f16* x0lo   = (f16*)p;            p += (size_t)BB*DD*2;
  f16* h0hi   = (f16*)p;            p += (size_t)BH*2;
  f16* h0lo   = (f16*)p;            p += (size_t)BH*2;
  unsigned* X = (unsigned*)p;       p += (size_t)4*8*XSLOT_U32*4;   // 4 MB
  float* bh   = (float*)p;          p += (size_t)SS*BH*4;
  float* bc   = (float*)p;          p += (size_t)SS*BH*4;
  float* bias0= (float*)p;          p += G4H*4;
  float* bias1= (float*)p;          p += G4H*4;
  float4* stepc = (float4*)p;       p += (size_t)TT*16;
  int*  flags = (int*)p;            p += 256*4;
  float* outp = (float*)d_out;

  hipLaunchKernelGGL(prep_wbig16, dim3(32, 8), dim3(256), 0, stream,
                     W_ih, W_hh, W_lin, Wbig16);
  hipLaunchKernelGGL(prep_bias, dim3(8), dim3(256), 0, stream,
                     b_ih, b_hh, W_ih, b_lin, bias0, bias1);
  hipLaunchKernelGGL(prep_cvtw, dim3(6656), dim3(256), 0, stream,
                     W_ih, W_hh, W_lin, Wih16, Whh16, Wlin16);
  hipLaunchKernelGGL(prep_init, dim3(4096), dim3(256), 0, stream,
                     x0, h0, c0, w1, w2, bh, bc, x0hi, x0lo, h0hi, h0lo, stepc, flags);

  hipLaunchKernelGGL(lstm_persist, dim3(72), dim3(512), 0, stream,
                     x0hi, x0lo, h0hi, h0lo, c0, Wih16, Whh16, Wbig16, Wlin16,
                     bias0, bias1, b_lin, stepc, X, bh, bc, flags, outp);
}

// Round 9
// 2381.336 us; speedup vs baseline: 2.4740x; 1.3489x over previous
//
#include <hip/hip_runtime.h>
#include <math.h>

#define BB 256
#define TT 512
#define DD 256
#define HH 512
#define SS 8
#define G4H 2048
#define BH (BB*HH)          // 131072
#define OUT_BASE ((size_t)BB*TT*DD)
#define XSLOT_U32 8192      // 32 KB per group-slot: 32 rows x 256 u32 (fp16 pairs)

typedef _Float16 f16;
typedef __attribute__((ext_vector_type(8)))  _Float16 f16x8;
typedef __attribute__((ext_vector_type(16))) float    f32x16;

__device__ __forceinline__ float sigm(float x) { return 1.f / (1.f + __expf(-x)); }
__device__ __forceinline__ float ftanh(float x) {
  x = fminf(15.f, fmaxf(-15.f, x));
  float e = __expf(-2.f * x);
  return (1.f - e) / (1.f + e);
}

// ---------------- prep kernels ----------------

__global__ __launch_bounds__(256) void prep_wbig16(
    const float* __restrict__ W_ih, const float* __restrict__ W_hh,
    const float* __restrict__ W_lin, f16* __restrict__ Wbig16)
{
  __shared__ float As[64][20];
  __shared__ float Bs[16][68];
  const int n0 = blockIdx.x * 64;
  const int j0 = blockIdx.y * 64;
  const int tid = threadIdx.x;
  const int tn = tid >> 4, tj = tid & 15;
  float acc[4][4] = {};
  for (int k0 = 0; k0 < DD; k0 += 16) {
    { int r = tid >> 2, c = (tid & 3) * 4;
      *(float4*)&As[r][c] = *(const float4*)&W_ih[(size_t)(n0 + r) * DD + k0 + c]; }
    { int r = tid >> 4, c = (tid & 15) * 4;
      *(float4*)&Bs[r][c] = *(const float4*)&W_lin[(size_t)(k0 + r) * HH + j0 + c]; }
    __syncthreads();
    #pragma unroll
    for (int k = 0; k < 16; ++k) {
      float a[4], bv[4];
      #pragma unroll
      for (int i = 0; i < 4; ++i) a[i] = As[tn*4+i][k];
      #pragma unroll
      for (int m = 0; m < 4; ++m) bv[m] = Bs[k][tj*4+m];
      #pragma unroll
      for (int i = 0; i < 4; ++i)
        #pragma unroll
        for (int m = 0; m < 4; ++m)
          acc[i][m] = fmaf(a[i], bv[m], acc[i][m]);
    }
    __syncthreads();
  }
  #pragma unroll
  for (int i = 0; i < 4; ++i) {
    int n = n0 + tn*4 + i;
    #pragma unroll
    for (int m = 0; m < 4; ++m) {
      int j = j0 + tj*4 + m;
      Wbig16[(size_t)n*HH + j] = (f16)(acc[i][m] + W_hh[(size_t)n*HH + j]);
    }
  }
}

__global__ void prep_bias(const float* __restrict__ b_ih, const float* __restrict__ b_hh,
                          const float* __restrict__ W_ih, const float* __restrict__ b_lin,
                          float* __restrict__ bias0, float* __restrict__ bias1)
{
  int n = blockIdx.x * 256 + threadIdx.x;   // grid 8
  float s = b_ih[n] + b_hh[n];
  float d = 0.f;
  for (int k = 0; k < DD; ++k) d = fmaf(W_ih[(size_t)n*DD + k], b_lin[k], d);
  bias0[n] = s;
  bias1[n] = s + d;
}

#define NIH (G4H*DD)
#define NHH (G4H*HH)
__global__ void prep_cvtw(const float* __restrict__ W_ih, const float* __restrict__ W_hh,
                          const float* __restrict__ W_lin,
                          f16* __restrict__ Wih16, f16* __restrict__ Whh16,
                          f16* __restrict__ Wlin16)
{
  int e = blockIdx.x * 256 + threadIdx.x;   // grid 6656
  if (e < NIH) Wih16[e] = (f16)W_ih[e];
  else if (e < NIH + NHH) Whh16[e - NIH] = (f16)W_hh[e - NIH];
  else Wlin16[e - NIH - NHH] = (f16)W_lin[e - NIH - NHH];
}

__global__ void prep_init(const float* __restrict__ x0, const float* __restrict__ h0,
                          const float* __restrict__ c0,
                          const int* __restrict__ w1, const int* __restrict__ w2,
                          float* __restrict__ bh, float* __restrict__ bc,
                          f16* __restrict__ x0hi, f16* __restrict__ x0lo,
                          f16* __restrict__ h0hi, f16* __restrict__ h0lo,
                          float4* __restrict__ stepc,
                          int* __restrict__ flags)
{
  int e = blockIdx.x * 256 + threadIdx.x;   // grid 4096 -> 1048576
  int r = e & (BH - 1);
  bh[e] = h0[r];
  bc[e] = c0[r];
  if (e < BH) {
    float v = h0[e];
    f16 hi = (f16)v;
    h0hi[e] = hi;
    h0lo[e] = (f16)(v - (float)hi);
  }
  if (e < BB*DD) {
    int b = e >> 8, d = e & 255;
    float v = x0[(size_t)b*(TT*DD) + d];
    f16 hi = (f16)v;
    x0hi[e] = hi;
    x0lo[e] = (f16)(v - (float)hi);
  }
  if (e < TT) {
    float a1 = (float)w1[e], a2 = (float)w2[e];
    stepc[e] = make_float4(a1, a2, 1.f / (a1 + a2), 0.f);
  }
  if (e < 256) flags[e] = 0;
}

// ---------------- persistent main kernel ----------------

// Stage one 32 KB group-slot (single fp16 plane, 32 rows x 512 cols) into
// linear LDS via global_load_lds (16B/lane, sc0|sc1 for L3 coherence).
// Bank-conflict XOR swizzle applied on the per-lane GLOBAL source address.
__device__ __forceinline__ void stageG(const unsigned* __restrict__ Xs,
                                       f16* lds, int tid) {
  const int lane = tid & 63;
  const int wv = tid >> 6;
  #pragma unroll
  for (int i = 0; i < 4; ++i) {
    int r = wv * 4 + i;                 // row 0..31 (wave-uniform)
    const char* src = (const char*)Xs + (size_t)r * 1024 +
                      (size_t)((lane ^ (r & 31)) & 63) * 16;
    __builtin_amdgcn_global_load_lds(
        (const __attribute__((address_space(1))) void*)src,
        (__attribute__((address_space(3))) void*)((char*)lds + r * 1024),
        16, 0, 0x11 /* sc0|sc1 */);
  }
}

// K=512 single-plane MFMA GEMM from swizzled LDS, W frags in registers.
__device__ __forceinline__ f32x16 gemmS(const f16x8 (&w)[32], const f16* lds, int lane) {
  const int row = lane & 31;
  const int sel = lane >> 5;
  const int rb  = row * 1024;
  const int key = row & 31;
  f32x16 acc;
  #pragma unroll
  for (int i = 0; i < 16; ++i) acc[i] = 0.f;
  #pragma unroll
  for (int ks = 0; ks < 32; ++ks) {
    int gk = 2 * ks + sel;
    int off = rb + (((gk & 31) ^ key) << 4) + ((gk & 32) << 4);
    f16x8 a = *(const f16x8*)((const char*)lds + off);
    acc = __builtin_amdgcn_mfma_f32_32x32x16_f16(a, w[ks], acc, 0, 0, 0);
  }
  return acc;
}

// 72 blocks x 512 threads (8 waves).
// bid 0..63: gates. grp = bid&7 owns batch rows [32g,32g+32); role = bid>>3 owns
//            j-slice [64r,64r+64) x 4 gates (wave wv: gate wv&3, j-half wv>>2).
// bid 64..71: out-projection block per group, lagging on a 4-slot ring.
// flags[grp*16 + r] = steps completed by gates block r; [grp*16+8] = out block.
__global__ __launch_bounds__(512, 2) void lstm_persist(
    const f16* __restrict__ x0hi, const f16* __restrict__ x0lo,
    const f16* __restrict__ h0hi, const f16* __restrict__ h0lo,
    const float* __restrict__ c0,
    const f16* __restrict__ Wih16, const f16* __restrict__ Whh16,
    const f16* __restrict__ Wbig16, const f16* __restrict__ Wlin16,
    const float* __restrict__ bias0, const float* __restrict__ bias1,
    const float* __restrict__ b_lin,
    const float4* __restrict__ stepc,
    unsigned* __restrict__ X,                 // 4 slots x 8 grp x XSLOT_U32
    float* __restrict__ bh, float* __restrict__ bc,
    int* __restrict__ flags,
    float* __restrict__ outp)
{
  __shared__ f16 LdsA[16384];       // 32 KB single plane
  __shared__ float gbuf[8192];      // 32 KB: [gate][32 b][64 j]

  const int tid  = threadIdx.x;
  const int lane = tid & 63;
  const int wv   = tid >> 6;            // wave 0..7
  const int bid  = blockIdx.x;
  const bool isG = bid < 64;
  const int grp  = isG ? (bid & 7) : (bid - 64);
  const int role = bid >> 3;            // gates only: 0..7
  const int b0   = grp * 32;
  const int row  = lane & 31;
  const int ksel8 = (lane >> 5) * 8;

  int* gflag = flags + grp * 16;

  // ---- persistent W fragments (1 N-tile x K=512 -> 128 VGPR) ----
  int wrow;
  const f16* wbase;
  if (isG) {
    wrow  = (wv & 3) * 512 + role * 64 + (wv >> 2) * 32 + row;  // W_big row
    wbase = Wbig16 + (size_t)wrow * HH;
  } else {
    wrow  = wv * 32 + row;                                      // W_lin row (d-col)
    wbase = Wlin16 + (size_t)wrow * HH;
  }
  f16x8 wreg[32];
  #pragma unroll
  for (int ks = 0; ks < 32; ++ks)
    wreg[ks] = *(const f16x8*)(wbase + ks * 16 + ksel8);

  if (isG) {
    // ---- per-thread epilogue constants ----
    int   eidx[4];
    float creg[4];
    const int jl = tid & 63;
    const int jg = role * 64 + jl;
    const float bI = bias1[jg],        bF = bias1[512 + jg];
    const float bG = bias1[1024 + jg], bO = bias1[1536 + jg];
    #pragma unroll
    for (int i = 0; i < 4; ++i) {
      int c = i * 512 + tid;
      int bl = c >> 6;
      eidx[i] = (b0 + bl) * HH + jg;
      creg[i] = c0[eidx[i]];
    }

    for (int t = 0; t < TT; ++t) {
      if (t > 0) {
        // wait for all 8 gates blocks of this group; lane 8 guards slot reuse
        if (tid < 8) {
          while (__hip_atomic_load(&gflag[tid], __ATOMIC_RELAXED,
                                   __HIP_MEMORY_SCOPE_AGENT) < t) {}
        } else if (tid == 8 && t >= 4) {
          while (__hip_atomic_load(&gflag[8], __ATOMIC_RELAXED,
                                   __HIP_MEMORY_SCOPE_AGENT) < t - 3) {}
        }
        __syncthreads();
        stageG(X + (size_t)(((t - 1) & 3) * 8 + grp) * XSLOT_U32, LdsA, tid);
      }

      // prefetch step constants + skip reads (overlap with staging flight)
      const float4 sc = stepc[t];
      const int pos = t & (SS - 1);
      float shv[4], scv[4];
      #pragma unroll
      for (int i = 0; i < 4; ++i) {
        int bx = pos * BH + eidx[i];
        shv[i] = bh[bx];
        scv[i] = bc[bx];
      }

      f32x16 acc;
      if (t == 0) {
        #pragma unroll
        for (int i = 0; i < 16; ++i) acc[i] = 0.f;
        const f16* arh = x0hi + (size_t)(b0 + row) * DD;
        const f16* arl = x0lo + (size_t)(b0 + row) * DD;
        const f16* w1p = Wih16 + (size_t)wrow * DD;
        #pragma unroll
        for (int ks = 0; ks < 16; ++ks) {         // K=256: x0 @ W_ih^T
          int ko = ks * 16 + ksel8;
          f16x8 w = *(const f16x8*)(w1p + ko);
          acc = __builtin_amdgcn_mfma_f32_32x32x16_f16(*(const f16x8*)(arh + ko), w, acc, 0,0,0);
          acc = __builtin_amdgcn_mfma_f32_32x32x16_f16(*(const f16x8*)(arl + ko), w, acc, 0,0,0);
        }
        const f16* brh = h0hi + (size_t)(b0 + row) * HH;
        const f16* brl = h0lo + (size_t)(b0 + row) * HH;
        const f16* w2p = Whh16 + (size_t)wrow * HH;
        #pragma unroll
        for (int ks = 0; ks < 32; ++ks) {         // K=512: h0 @ W_hh^T
          int ko = ks * 16 + ksel8;
          f16x8 w = *(const f16x8*)(w2p + ko);
          acc = __builtin_amdgcn_mfma_f32_32x32x16_f16(*(const f16x8*)(brh + ko), w, acc, 0,0,0);
          acc = __builtin_amdgcn_mfma_f32_32x32x16_f16(*(const f16x8*)(brl + ko), w, acc, 0,0,0);
        }
      } else {
        __syncthreads();                 // staging complete (vmcnt drained here)
        acc = gemmS(wreg, LdsA, lane);
      }

      // acc -> gbuf [gate][b][j]
      {
        const int col = lane & 31;
        const int g4 = wv & 3, jh = wv >> 2;
        #pragma unroll
        for (int rg = 0; rg < 16; ++rg) {
          int m = (rg & 3) + ((rg >> 2) << 3) + ((lane >> 5) << 2);
          gbuf[g4 * 2048 + m * 64 + jh * 32 + col] = acc[rg];
        }
      }
      __syncthreads();

      // epilogue phase 1: gate math up to ch, publish X, flag
      const float a1 = sc.x, a2 = sc.y, nrm = sc.z;
      float baI = bI, baF = bF, baG = bG, baO = bO;
      if (t == 0) {
        baI = bias0[jg];        baF = bias0[512 + jg];
        baG = bias0[1024 + jg]; baO = bias0[1536 + jg];
      }
      unsigned* Xw = X + (size_t)((t & 3) * 8 + grp) * XSLOT_U32;
      float hnv[4], cnv[4], chv[4];
      #pragma unroll
      for (int i = 0; i < 4; ++i) {
        int c = i * 512 + tid;
        int bl = c >> 6;
        float pi = gbuf[c]        + baI;
        float pf = gbuf[2048 + c] + baF;
        float pg = gbuf[4096 + c] + baG;
        float po = gbuf[6144 + c] + baO;
        float i_ = sigm(pi), f_ = sigm(pf), o_ = sigm(po), g_ = ftanh(pg);
        float cnew = fmaf(f_, creg[i], i_ * g_);
        float hnew = o_ * ftanh(cnew);
        float ch = (a1 * hnew + a2 * ftanh(shv[i])) * nrm;
        hnv[i] = hnew; cnv[i] = cnew; chv[i] = ch;
        f16 hv = (f16)ch;
        unsigned hb = (unsigned)*(unsigned short*)&hv;
        unsigned part = (unsigned)__shfl_xor((int)hb, 1);
        if ((tid & 1) == 0)
          __hip_atomic_store(&Xw[bl * 256 + (jg >> 1)], hb | (part << 16),
                             __ATOMIC_RELAXED, __HIP_MEMORY_SCOPE_AGENT);
      }
      __syncthreads();                 // drains X stores of all waves (vmcnt 0)
      if (tid == 0)
        __hip_atomic_store(&gflag[role], t + 1, __ATOMIC_RELAXED,
                           __HIP_MEMORY_SCOPE_AGENT);

      // epilogue phase 2 (off critical path): cc, skip buffers, finals
      #pragma unroll
      for (int i = 0; i < 4; ++i) {
        float cc = (a1 * cnv[i] + a2 * ftanh(scv[i])) * nrm;
        creg[i] = cc;
        int bx = pos * BH + eidx[i];
        bh[bx] = hnv[i];
        bc[bx] = cnv[i];
        if (t == TT - 1) {
          __builtin_nontemporal_store(chv[i], &outp[OUT_BASE + eidx[i]]);       // h_fin
          __builtin_nontemporal_store(cc,     &outp[OUT_BASE + BH + eidx[i]]);  // c_fin
        }
      }
    }
  } else {
    // ---------- lagging out-projection block (one per group) ----------
    const float bld = b_lin[wrow];
    for (int s = 0; s < TT; ++s) {
      if (tid < 8) {
        while (__hip_atomic_load(&gflag[tid], __ATOMIC_RELAXED,
                                 __HIP_MEMORY_SCOPE_AGENT) < s + 1) {}
      }
      __syncthreads();
      stageG(X + (size_t)((s & 3) * 8 + grp) * XSLOT_U32, LdsA, tid);
      __syncthreads();                 // staging complete
      f32x16 acc = gemmS(wreg, LdsA, lane);
      __syncthreads();                 // all waves' ds_reads of the slot done
      if (tid == 0)
        __hip_atomic_store(&gflag[8], s + 1, __ATOMIC_RELAXED,
                           __HIP_MEMORY_SCOPE_AGENT);
      const size_t tbase = (size_t)s * DD + wrow;
      #pragma unroll
      for (int rg = 0; rg < 16; ++rg) {
        int m = (rg & 3) + ((rg >> 2) << 3) + ((lane >> 5) << 2);
        __builtin_nontemporal_store(acc[rg] + bld,
                                    &outp[(size_t)(b0 + m) * (TT*DD) + tbase]);
      }
    }
  }
}

// ---------------- host launch ----------------

extern "C" void kernel_launch(void* const* d_in, const int* in_sizes, int n_in,
                              void* d_out, int out_size, void* d_ws, size_t ws_size,
                              hipStream_t stream)
{
  const float* x0    = (const float*)d_in[0];
  const float* h0    = (const float*)d_in[1];
  const float* c0    = (const float*)d_in[2];
  const float* W_ih  = (const float*)d_in[3];
  const float* W_hh  = (const float*)d_in[4];
  const float* b_ih  = (const float*)d_in[5];
  const float* b_hh  = (const float*)d_in[6];
  const float* W_lin = (const float*)d_in[7];
  const float* b_lin = (const float*)d_in[8];
  const int*   w1    = (const int*)d_in[9];
  const int*   w2    = (const int*)d_in[10];

  char* p = (char*)d_ws;
  f16* Wbig16 = (f16*)p;            p += (size_t)G4H*HH*2;
  f16* Wih16  = (f16*)p;            p += (size_t)G4H*DD*2;
  f16* Whh16  = (f16*)p;            p += (size_t)G4H*HH*2;
  f16* Wlin16 = (f16*)p;            p += (size_t)DD*HH*2;
  f16* x0hi   = (f16*)p;            p += (size_t)BB*DD*2;
  f16* x0lo   = (f16*)p;            p += (size_t)BB*DD*2;
  f16* h0hi   = (f16*)p;            p += (size_t)BH*2;
  f16* h0lo   = (f16*)p;            p += (size_t)BH*2;
  unsigned* X = (unsigned*)p;       p += (size_t)4*8*XSLOT_U32*4;   // 1 MB
  float* bh   = (float*)p;          p += (size_t)SS*BH*4;
  float* bc   = (float*)p;          p += (size_t)SS*BH*4;
  float* bias0= (float*)p;          p += G4H*4;
  float* bias1= (float*)p;          p += G4H*4;
  float4* stepc = (float4*)p;       p += (size_t)TT*16;
  int*  flags = (int*)p;            p += 256*4;
  float* outp = (float*)d_out;

  hipLaunchKernelGGL(prep_wbig16, dim3(32, 8), dim3(256), 0, stream,
                     W_ih, W_hh, W_lin, Wbig16);
  hipLaunchKernelGGL(prep_bias, dim3(8), dim3(256), 0, stream,
                     b_ih, b_hh, W_ih, b_lin, bias0, bias1);
  hipLaunchKernelGGL(prep_cvtw, dim3(6656), dim3(256), 0, stream,
                     W_ih, W_hh, W_lin, Wih16, Whh16, Wlin16);
  hipLaunchKernelGGL(prep_init, dim3(4096), dim3(256), 0, stream,
                     x0, h0, c0, w1, w2, bh, bc, x0hi, x0lo, h0hi, h0lo, stepc, flags);

  hipLaunchKernelGGL(lstm_persist, dim3(72), dim3(512), 0, stream,
                     x0hi, x0lo, h0hi, h0lo, c0, Wih16, Whh16, Wbig16, Wlin16,
                     bias0, bias1, b_lin, stepc, X, bh, bc, flags, outp);
}